// Round 6
// baseline (638.668 us; speedup 1.0000x reference)
//
#include <hip/hip_runtime.h>
#include <hip/hip_bf16.h>

// z: (8,2048,64) f32 -> N=16384, D=64 ; codebook: (8192,64) f32
// outputs (f32, concat): z_q_st[1048576], vq_loss[1], idx[16384],
//   new_codebook[524288], new_cs[8192], new_ws[524288]

#define NQ 16384
#define KC 8192
#define DD 64
#define KSPLIT 16
#define CHUNK (KC / KSPLIT)

using f4 = __attribute__((ext_vector_type(4))) float;
using f2 = __attribute__((ext_vector_type(2))) float;

#define R16(M) M(0) M(1) M(2) M(3) M(4) M(5) M(6) M(7) \
               M(8) M(9) M(10) M(11) M(12) M(13) M(14) M(15)

// ---------------- workspace layout (floats) ----------------
// [0)        dw          524288
// [524288)   cs          8192
// [532480)   parts       64      (sumsq spread buckets)
// [532544)   ema_sum     1       (sum of ema_cluster_size)
// [532608)   cnorm       8192
// [540800)   pmin        262144
// [802944)   pidx (int)  262144

__global__ __launch_bounds__(256) void k_cnorm(const float* __restrict__ cb,
                                               const float* __restrict__ ema_cs,
                                               float* __restrict__ cnorm,
                                               float* __restrict__ ema_sum) {
  int k = blockIdx.x * 256 + threadIdx.x;
  const float* __restrict__ r = cb + (size_t)k * DD;
  float a0 = 0.f, a1 = 0.f, a2 = 0.f, a3 = 0.f;
#pragma unroll
  for (int d = 0; d < DD; d += 4) {
    a0 = fmaf(r[d], r[d], a0);
    a1 = fmaf(r[d + 1], r[d + 1], a1);
    a2 = fmaf(r[d + 2], r[d + 2], a2);
    a3 = fmaf(r[d + 3], r[d + 3], a3);
  }
  cnorm[k] = (a0 + a1) + (a2 + a3);
  // block-partial sum of ema_cs -> ema_sum (for n in k_final)
  float su = ema_cs[k];
#pragma unroll
  for (int off = 1; off < 64; off <<= 1) su += __shfl_xor(su, off, 64);
  __shared__ float ss[4];
  if ((threadIdx.x & 63) == 0) ss[threadIdx.x >> 6] = su;
  __syncthreads();
  if (threadIdx.x == 0) atomicAdd(ema_sum, ss[0] + ss[1] + ss[2] + ss[3]);
}

// lane = query; z row in VGPRs. amdgpu_waves_per_eu(2,2) caps occupancy at
// 2 waves/EU so the scheduler has NO incentive to spill below 256 VGPRs --
// this (not restrict/asm/volatile tricks) removes the occupancy-maximizing
// heuristic that spilled the 64-float z row in R2-R5. Code index is
// wave-uniform -> codebook rows lower to s_load on the scalar pipe.
// Distance arithmetic bit-identical to passing R2/R3/R5 kernels.
__global__ __launch_bounds__(256)
__attribute__((amdgpu_waves_per_eu(2, 2))) void k_argmin(
    const float* __restrict__ z, const float* __restrict__ cb,
    const float* __restrict__ cnorm, float* __restrict__ pmin,
    int* __restrict__ pidx) {
  const int q = blockIdx.x * 256 + threadIdx.x;
  const int ks = blockIdx.y;

  const volatile f4* zp = (const volatile f4*)(z + (size_t)q * DD);
#define LZ(i) const f4 z##i = zp[i];
  R16(LZ)
#undef LZ

  f2 XA = {0.f, 0.f}, XB = {0.f, 0.f};
#define XS(i)                                            \
  XA = __builtin_elementwise_fma(z##i.lo, z##i.lo, XA);  \
  XB = __builtin_elementwise_fma(z##i.hi, z##i.hi, XB);
  R16(XS)
#undef XS
  const float xnorm = (XA.x + XA.y) + (XB.x + XB.y);

  float best = 3.4e38f;
  int bi = 0;
  const int c0 = ks * CHUNK;
#pragma unroll 2
  for (int c = c0; c < c0 + CHUNK; ++c) {
    const f4* __restrict__ cp = (const f4*)(cb + (size_t)c * DD);
    f2 A = {0.f, 0.f}, B = {0.f, 0.f};
#define DS(i)                                         \
  {                                                   \
    const f4 cc = cp[i];                              \
    A = __builtin_elementwise_fma(cc.lo, z##i.lo, A); \
    B = __builtin_elementwise_fma(cc.hi, z##i.hi, B); \
  }
    R16(DS)
#undef DS
    const float dot = (A.x + A.y) + (B.x + B.y);
    const float dist = (xnorm - 2.0f * dot) + cnorm[c];
    if (dist < best) { best = dist; bi = c; }
  }
  pmin[(size_t)ks * NQ + q] = best;
  pidx[(size_t)ks * NQ + q] = bi;
}

// Fused: per-query 16-way argmin merge (shuffle), z_q gather, idx write,
// loss partial (spread buckets), cs/dw scatter. One wave per query.
__global__ __launch_bounds__(256) void k_assign(
    const float* __restrict__ z, const float* __restrict__ cb,
    const float* __restrict__ pmin, const int* __restrict__ pidx,
    float* __restrict__ out_zq, float* __restrict__ out_idx,
    float* __restrict__ dw, float* __restrict__ cs,
    float* __restrict__ parts) {
  const int t = threadIdx.x;
  const int d = t & 63;
  const int q = blockIdx.x * 4 + (t >> 6);

  const int s = d & 15;
  float v = pmin[(size_t)s * NQ + q];
  int i = pidx[(size_t)s * NQ + q];
#pragma unroll
  for (int off = 1; off < 16; off <<= 1) {
    float v2 = __shfl_xor(v, off, 64);
    int i2 = __shfl_xor(i, off, 64);
    if (v2 < v || (v2 == v && i2 < i)) { v = v2; i = i2; }
  }
  const int k = i;  // all lanes agree

  const float zv = z[(size_t)q * DD + d];
  const float cv = cb[(size_t)k * DD + d];
  out_zq[(size_t)q * DD + d] = cv;  // z + (z_q - z)
  const float diff = zv - cv;
  float sq = diff * diff;
#pragma unroll
  for (int off = 1; off < 64; off <<= 1) sq += __shfl_xor(sq, off, 64);
  if (d == 0) {
    out_idx[q] = (float)k;  // exact in f32 (k < 8192)
    atomicAdd(&cs[k], 1.0f);
    atomicAdd(&parts[blockIdx.x & 63], sq);
  }
  atomicAdd(&dw[(size_t)k * DD + d], zv);
}

// Fused newcs + finalout: n is computable without a grid sync because
// sum(cluster_size) == NQ exactly, so n = 0.99*sum(ema_cs) + 0.01*NQ.
__global__ __launch_bounds__(256) void k_final(
    const float* __restrict__ ema_cs, const float* __restrict__ cs,
    const float* __restrict__ ema_ws, const float* __restrict__ dw,
    const float* __restrict__ ema_sum, const float* __restrict__ parts,
    float* __restrict__ out_ncs, float* __restrict__ out_ncb,
    float* __restrict__ out_nws, float* __restrict__ out_loss) {
  const int i = blockIdx.x * 256 + threadIdx.x;
  const int k = i >> 6;
  const int d = i & 63;

  if (blockIdx.x == 0 && threadIdx.x < 64) {
    float sv = parts[threadIdx.x];
#pragma unroll
    for (int off = 1; off < 64; off <<= 1) sv += __shfl_xor(sv, off, 64);
    if (threadIdx.x == 0) *out_loss = 1.25f * sv * (1.0f / 1048576.0f);
  }

  const float n = 0.99f * (*ema_sum) + 0.01f * 16384.0f;
  const float v = 0.99f * ema_cs[k] + 0.01f * cs[k];
  if (d == 0) out_ncs[k] = v;
  const float smoothed = (v + 1e-5f) / (n + (float)KC * 1e-5f) * n;
  const float nws = 0.99f * ema_ws[i] + 0.01f * dw[i];
  out_nws[i] = nws;
  out_ncb[i] = nws / smoothed;
}

extern "C" void kernel_launch(void* const* d_in, const int* in_sizes, int n_in,
                              void* d_out, int out_size, void* d_ws,
                              size_t ws_size, hipStream_t stream) {
  const float* z = (const float*)d_in[0];
  const float* cb = (const float*)d_in[1];
  const float* ema_cs = (const float*)d_in[2];
  const float* ema_ws = (const float*)d_in[3];

  float* out = (float*)d_out;
  float* zq_out = out;              // 1048576
  float* loss_out = out + 1048576;  // 1
  float* idx_out = out + 1048577;   // 16384
  float* ncb_out = out + 1064961;   // 524288
  float* ncs_out = out + 1589249;   // 8192
  float* nws_out = out + 1597441;   // 524288

  float* ws = (float*)d_ws;
  float* dw = ws;                    // 524288
  float* cs = ws + 524288;           // 8192
  float* parts = ws + 532480;        // 64
  float* ema_sum = ws + 532544;      // 1
  float* cnorm = ws + 532608;        // 8192
  float* pmin = ws + 540800;         // 262144
  int* pidx = (int*)(ws + 802944);   // 262144

  // zero dw..ema_sum (contiguous prefix)
  hipMemsetAsync(d_ws, 0, (size_t)532545 * sizeof(float), stream);

  k_cnorm<<<KC / 256, 256, 0, stream>>>(cb, ema_cs, cnorm, ema_sum);
  k_argmin<<<dim3(NQ / 256, KSPLIT), 256, 0, stream>>>(z, cb, cnorm, pmin,
                                                       pidx);
  k_assign<<<NQ / 4, 256, 0, stream>>>(z, cb, pmin, pidx, zq_out, idx_out, dw,
                                       cs, parts);
  k_final<<<KC * DD / 256, 256, 0, stream>>>(ema_cs, cs, ema_ws, dw, ema_sum,
                                             parts, ncs_out, ncb_out, nws_out,
                                             loss_out);
}

// Round 7
// 300.391 us; speedup vs baseline: 2.1261x; 2.1261x over previous
//
#include <hip/hip_runtime.h>
#include <hip/hip_bf16.h>

// z: (8,2048,64) f32 -> N=16384, D=64 ; codebook: (8192,64) f32
// outputs (f32, concat): z_q_st[1048576], vq_loss[1], idx[16384],
//   new_codebook[524288], new_cs[8192], new_ws[524288]
//
// Distance argmin via f16-split MFMA: x = xh + xl (two f16 terms, ~22 mantissa
// bits). dot(x,c) ~= Xh.Ch + Xh.Cl + Xl.Ch  ==  one K=192 GEMM with
// A = [Xh|Xh|Xl] (dedup: [Xh|Xl] stored, Xh-frags reused), B = [Ch|Cl|Ch].
// argmin_c ||x-c||^2 == argmax_c (dot - 0.5*||c||^2): xnorm drops out.

#define NQ 16384
#define KC 8192
#define DD 64
#define NSPLIT 8
#define CSPLIT (KC / NSPLIT)     // 1024 codes per (block) job
#define GROUP 128                // codes staged in LDS per barrier
#define NGROUP (CSPLIT / GROUP)  // 8
#define NTILE (GROUP / 16)       // 8 MFMA c-tiles per staged group

typedef _Float16 half8 __attribute__((ext_vector_type(8)));
typedef float f32x4 __attribute__((ext_vector_type(4)));

// ---------------- workspace layout (floats) ----------------
// [0)        dw          524288
// [524288)   cs          8192
// [532480)   parts       64     (sumsq spread buckets)
// [532544)   ema_sum     1
// [532608)   hcn         8192   (0.5*||c||^2)
// [540800)   pmax        131072 (8 x 16384 partial max-u)
// [671872)   pidx (int)  131072
// [802944)   Ax  f16 16384x128  (=1048576 floats)  [Xh|Xl]
// [1851520)  Cx  f16  8192x128  (= 524288 floats)  [Ch|Cl]
// total 2375808 floats = 9.5 MB

__global__ __launch_bounds__(256) void k_prep(
    const float* __restrict__ z, const float* __restrict__ cb,
    const float* __restrict__ ema_cs, _Float16* __restrict__ Ax,
    _Float16* __restrict__ Cx, float* __restrict__ hcn,
    float* __restrict__ ema_sum) {
  const int b = blockIdx.x;
  const int t = threadIdx.x;
  const int w = t >> 6, d = t & 63;
  const int r = b * 4 + w;
  if (r < KC) {
    float v = cb[(size_t)r * DD + d];
    _Float16 h = (_Float16)v;
    _Float16 l = (_Float16)(v - (float)h);
    Cx[(size_t)r * 128 + d] = h;
    Cx[(size_t)r * 128 + 64 + d] = l;
    float s = v * v;
#pragma unroll
    for (int off = 1; off < 64; off <<= 1) s += __shfl_xor(s, off, 64);
    if (d == 0) hcn[r] = 0.5f * s;
  } else {
    int q = r - KC;
    float v = z[(size_t)q * DD + d];
    _Float16 h = (_Float16)v;
    _Float16 l = (_Float16)(v - (float)h);
    Ax[(size_t)q * 128 + d] = h;
    Ax[(size_t)q * 128 + 64 + d] = l;
  }
  if (b < 32) {  // fold sum(ema_cs) for n in k_final
    float su = ema_cs[b * 256 + t];
#pragma unroll
    for (int off = 1; off < 64; off <<= 1) su += __shfl_xor(su, off, 64);
    __shared__ float ss[4];
    if (d == 0) ss[w] = su;
    __syncthreads();
    if (t == 0) atomicAdd(ema_sum, ss[0] + ss[1] + ss[2] + ss[3]);
  }
}

// MFMA argmax. Wave = 32 queries (2 16x16 q-tiles), block job = 1024 codes.
// 16x16x32 f16 layouts (HW-verified family): A: lane holds
// A[m=lane&15][k=(lane>>4)*8+j]; B: lane holds B[k=(lane>>4)*8+j][n=lane&15];
// C/D: col=lane&15 (code), row=(lane>>4)*4+reg (query).
__global__ __launch_bounds__(256) void k_mfma(
    const _Float16* __restrict__ Ax, const _Float16* __restrict__ Cx,
    const float* __restrict__ hcn, float* __restrict__ pmax,
    int* __restrict__ pidx) {
  __shared__ _Float16 Bs[GROUP * 200];
  const int t = threadIdx.x;
  const int lane = t & 63;
  const int w = t >> 6;
  const int split = blockIdx.y;
  const int Qw = blockIdx.x * 128 + w * 32;
  const int n16 = lane & 15;
  const int quad = lane >> 4;

  const half8* __restrict__ A8 = (const half8*)Ax;
  half8 aH0[2], aH1[2], aL0[2], aL1[2];
#pragma unroll
  for (int qt = 0; qt < 2; ++qt) {
    const size_t rowc = (size_t)(Qw + qt * 16 + n16) * 16;
    aH0[qt] = A8[rowc + quad];       // Xh k in [0,32)
    aH1[qt] = A8[rowc + 4 + quad];   // Xh k in [32,64)
    aL0[qt] = A8[rowc + 8 + quad];   // Xl k in [0,32)
    aL1[qt] = A8[rowc + 12 + quad];  // Xl k in [32,64)
  }

  float best[2][4];
  int bidx[2][4];
#pragma unroll
  for (int qt = 0; qt < 2; ++qt)
#pragma unroll
    for (int r = 0; r < 4; ++r) {
      best[qt][r] = -3.4e38f;
      bidx[qt][r] = 0;
    }

  const int Cjob = split * CSPLIT;
  const half8* __restrict__ C8 = (const half8*)Cx;
  const int srow = t >> 1, shalf = t & 1;

  for (int g = 0; g < NGROUP; ++g) {
    const int C0 = Cjob + g * GROUP;
    __syncthreads();
    {  // stage 128 code rows -> LDS [Ch | Cl | Ch-dup], row stride 200 halves
      const size_t src = (size_t)(C0 + srow) * 16 + shalf * 8;
      _Float16* drow = &Bs[srow * 200 + shalf * 64];
#pragma unroll
      for (int j = 0; j < 8; ++j) {
        half8 v = C8[src + j];
        *(half8*)(drow + j * 8) = v;
        if (!shalf) *(half8*)(drow + 128 + j * 8) = v;  // Ch duplicate
      }
    }
    __syncthreads();
#pragma unroll
    for (int tt = 0; tt < NTILE; ++tt) {
      const _Float16* brow = &Bs[(tt * 16 + n16) * 200 + quad * 8];
      const half8 b0 = *(const half8*)(brow);        // Ch [0,32)
      const half8 b1 = *(const half8*)(brow + 32);   // Ch [32,64)
      const half8 b2 = *(const half8*)(brow + 64);   // Cl [0,32)
      const half8 b3 = *(const half8*)(brow + 96);   // Cl [32,64)
      const half8 b4 = *(const half8*)(brow + 128);  // Ch dup [0,32)
      const half8 b5 = *(const half8*)(brow + 160);  // Ch dup [32,64)
      const int c = C0 + tt * 16 + n16;
      const float cn = hcn[c];
#pragma unroll
      for (int qt = 0; qt < 2; ++qt) {
        f32x4 acc = {0.f, 0.f, 0.f, 0.f};
        acc = __builtin_amdgcn_mfma_f32_16x16x32_f16(aH0[qt], b0, acc, 0, 0, 0);
        acc = __builtin_amdgcn_mfma_f32_16x16x32_f16(aH1[qt], b1, acc, 0, 0, 0);
        acc = __builtin_amdgcn_mfma_f32_16x16x32_f16(aH0[qt], b2, acc, 0, 0, 0);
        acc = __builtin_amdgcn_mfma_f32_16x16x32_f16(aH1[qt], b3, acc, 0, 0, 0);
        acc = __builtin_amdgcn_mfma_f32_16x16x32_f16(aL0[qt], b4, acc, 0, 0, 0);
        acc = __builtin_amdgcn_mfma_f32_16x16x32_f16(aL1[qt], b5, acc, 0, 0, 0);
#pragma unroll
        for (int r = 0; r < 4; ++r) {
          const float u = acc[r] - cn;  // maximize dot - 0.5||c||^2
          if (u > best[qt][r]) { best[qt][r] = u; bidx[qt][r] = c; }
        }
      }
    }
  }
#pragma unroll
  for (int qt = 0; qt < 2; ++qt)
#pragma unroll
    for (int r = 0; r < 4; ++r) {
      float u = best[qt][r];
      int c = bidx[qt][r];
#pragma unroll
      for (int off = 1; off < 16; off <<= 1) {
        const float u2 = __shfl_xor(u, off, 64);
        const int c2 = __shfl_xor(c, off, 64);
        if (u2 > u || (u2 == u && c2 < c)) { u = u2; c = c2; }
      }
      if (n16 == 0) {
        const int q = Qw + qt * 16 + quad * 4 + r;
        pmax[(size_t)split * NQ + q] = u;
        pidx[(size_t)split * NQ + q] = c;
      }
    }
}

__global__ __launch_bounds__(256) void k_assign(
    const float* __restrict__ z, const float* __restrict__ cb,
    const float* __restrict__ pmax, const int* __restrict__ pidx,
    float* __restrict__ out_zq, float* __restrict__ out_idx,
    float* __restrict__ dw, float* __restrict__ cs,
    float* __restrict__ parts) {
  const int t = threadIdx.x;
  const int d = t & 63;
  const int q = blockIdx.x * 4 + (t >> 6);

  const int s = d & 7;
  float v = pmax[(size_t)s * NQ + q];
  int i = pidx[(size_t)s * NQ + q];
#pragma unroll
  for (int off = 1; off < 8; off <<= 1) {
    const float v2 = __shfl_xor(v, off, 64);
    const int i2 = __shfl_xor(i, off, 64);
    if (v2 > v || (v2 == v && i2 < i)) { v = v2; i = i2; }
  }
  const int k = i;  // all lanes agree

  const float zv = z[(size_t)q * DD + d];
  const float cv = cb[(size_t)k * DD + d];
  out_zq[(size_t)q * DD + d] = cv;  // z + (z_q - z)
  const float diff = zv - cv;
  float sq = diff * diff;
#pragma unroll
  for (int off = 1; off < 64; off <<= 1) sq += __shfl_xor(sq, off, 64);
  if (d == 0) {
    out_idx[q] = (float)k;  // exact in f32 (k < 8192)
    atomicAdd(&cs[k], 1.0f);
    atomicAdd(&parts[blockIdx.x & 63], sq);
  }
  atomicAdd(&dw[(size_t)k * DD + d], zv);
}

__global__ __launch_bounds__(256) void k_final(
    const float* __restrict__ ema_cs, const float* __restrict__ cs,
    const float* __restrict__ ema_ws, const float* __restrict__ dw,
    const float* __restrict__ ema_sum, const float* __restrict__ parts,
    float* __restrict__ out_ncs, float* __restrict__ out_ncb,
    float* __restrict__ out_nws, float* __restrict__ out_loss) {
  const int i = blockIdx.x * 256 + threadIdx.x;
  const int k = i >> 6;
  const int d = i & 63;

  if (blockIdx.x == 0 && threadIdx.x < 64) {
    float sv = parts[threadIdx.x];
#pragma unroll
    for (int off = 1; off < 64; off <<= 1) sv += __shfl_xor(sv, off, 64);
    if (threadIdx.x == 0) *out_loss = 1.25f * sv * (1.0f / 1048576.0f);
  }

  const float n = 0.99f * (*ema_sum) + 0.01f * 16384.0f;
  const float v = 0.99f * ema_cs[k] + 0.01f * cs[k];
  if (d == 0) out_ncs[k] = v;
  const float smoothed = (v + 1e-5f) / (n + (float)KC * 1e-5f) * n;
  const float nws = 0.99f * ema_ws[i] + 0.01f * dw[i];
  out_nws[i] = nws;
  out_ncb[i] = nws / smoothed;
}

extern "C" void kernel_launch(void* const* d_in, const int* in_sizes, int n_in,
                              void* d_out, int out_size, void* d_ws,
                              size_t ws_size, hipStream_t stream) {
  const float* z = (const float*)d_in[0];
  const float* cb = (const float*)d_in[1];
  const float* ema_cs = (const float*)d_in[2];
  const float* ema_ws = (const float*)d_in[3];

  float* out = (float*)d_out;
  float* zq_out = out;              // 1048576
  float* loss_out = out + 1048576;  // 1
  float* idx_out = out + 1048577;   // 16384
  float* ncb_out = out + 1064961;   // 524288
  float* ncs_out = out + 1589249;   // 8192
  float* nws_out = out + 1597441;   // 524288

  float* ws = (float*)d_ws;
  float* dw = ws;                        // 524288
  float* cs = ws + 524288;               // 8192
  float* parts = ws + 532480;            // 64
  float* ema_sum = ws + 532544;          // 1
  float* hcn = ws + 532608;              // 8192
  float* pmax = ws + 540800;             // 131072
  int* pidx = (int*)(ws + 671872);       // 131072
  _Float16* Ax = (_Float16*)(ws + 802944);   // 16384x128 f16
  _Float16* Cx = (_Float16*)(ws + 1851520);  //  8192x128 f16

  hipMemsetAsync(d_ws, 0, (size_t)532545 * sizeof(float), stream);

  k_prep<<<(KC + NQ) / 4, 256, 0, stream>>>(z, cb, ema_cs, Ax, Cx, hcn,
                                            ema_sum);
  k_mfma<<<dim3(NQ / 128, NSPLIT), 256, 0, stream>>>(Ax, Cx, hcn, pmax, pidx);
  k_assign<<<NQ / 4, 256, 0, stream>>>(z, cb, pmax, pidx, zq_out, idx_out, dw,
                                       cs, parts);
  k_final<<<KC * DD / 256, 256, 0, stream>>>(ema_cs, cs, ema_ws, dw, ema_sum,
                                             parts, ncs_out, ncb_out, nws_out,
                                             loss_out);
}

// Round 9
// 273.673 us; speedup vs baseline: 2.3337x; 1.0976x over previous
//
#include <hip/hip_runtime.h>
#include <hip/hip_bf16.h>

// z: (8,2048,64) f32 -> N=16384, D=64 ; codebook: (8192,64) f32
// outputs (f32, concat): z_q_st[1048576], vq_loss[1], idx[16384],
//   new_codebook[524288], new_cs[8192], new_ws[524288]
//
// Distance argmin via f16-split MFMA: x = xh + xl. dot(x,c) ~= Xh.Ch + Xh.Cl
// + Xl.Ch. argmin ||x-c||^2 == argmax (dot - 0.5||c||^2). f16 conversion
// happens inside k_mfma; MFMA values and order bit-identical to passing R7.
// R8 bug fixed: full four A-frags per q-tile (k[0,32) AND k[32,64)).

#define NQ 16384
#define KC 8192
#define DD 64
#define NSPLIT 8
#define CSPLIT (KC / NSPLIT)     // 1024 codes per block job
#define GROUP 128                // codes staged in LDS per barrier
#define NGROUP (CSPLIT / GROUP)  // 8
#define NTILE (GROUP / 16)       // 8 MFMA c-tiles per staged group

typedef _Float16 half8 __attribute__((ext_vector_type(8)));
typedef _Float16 half4v __attribute__((ext_vector_type(4)));
typedef float f32x4 __attribute__((ext_vector_type(4)));

// ---------------- workspace layout (floats) ----------------
// [0)        dw          524288
// [524288)   cs          8192
// [532480)   parts       64     (sumsq spread buckets)
// [532544)   ema_sum     1
// [532608)   hcn         8192   (0.5*||c||^2)
// [540800)   pmax        131072 (8 x 16384 partial max-u)
// [671872)   pidx (int)  131072

__global__ __launch_bounds__(256) void k_prep(
    const float* __restrict__ cb, const float* __restrict__ ema_cs,
    float* __restrict__ hcn, float* __restrict__ ema_sum) {
  const int b = blockIdx.x;
  const int t = threadIdx.x;
  const int w = t >> 6, d = t & 63;
  const int r = b * 4 + w;
  float v = cb[(size_t)r * DD + d];
  float s = v * v;
#pragma unroll
  for (int off = 1; off < 64; off <<= 1) s += __shfl_xor(s, off, 64);
  if (d == 0) hcn[r] = 0.5f * s;
  if (b < 32) {
    float su = ema_cs[b * 256 + t];
#pragma unroll
    for (int off = 1; off < 64; off <<= 1) su += __shfl_xor(su, off, 64);
    __shared__ float ss[4];
    if (d == 0) ss[w] = su;
    __syncthreads();
    if (t == 0) atomicAdd(ema_sum, ss[0] + ss[1] + ss[2] + ss[3]);
  }
}

// MFMA argmax. Wave = 32 queries (2 16x16 q-tiles), block job = 1024 codes.
// LDS: frag-contiguous + XOR swizzle. Slot ((tt*4+plane)*64 + q*16 + (n^fs))
// holds the B half8 for tile tt, plane (0=Ch k[0,32) 1=Ch k[32,64)
// 2=Cl k[0,32) 3=Cl k[32,64)), quad q, code col n; fs = (plane&1)*4 + q.
// Reads lane-linear ds_read_b128 (conflict-free); stores uniform over banks.
__global__ __launch_bounds__(256) void k_mfma(
    const float* __restrict__ z, const float* __restrict__ cb,
    const float* __restrict__ hcn, float* __restrict__ pmax,
    int* __restrict__ pidx) {
  __shared__ _Float16 Bs[NTILE * 4 * 64 * 8];  // 32 KB
  const int t = threadIdx.x;
  const int lane = t & 63;
  const int w = t >> 6;
  const int split = blockIdx.y;
  const int Qw = blockIdx.x * 128 + w * 32;
  const int n16 = lane & 15;
  const int quad = lane >> 4;

  // A-frags: z rows -> f16 split in registers. Frag layout (16x16x32 f16):
  // lane holds A[m=lane&15][k=(lane>>4)*8+j]. Low half k in [0,32) from
  // d=quad*8+j; high half k in [32,64) from d=32+quad*8+j.
  const f32x4* __restrict__ z4 = (const f32x4*)z;
  half8 aH0[2], aH1[2], aL0[2], aL1[2];
#pragma unroll
  for (int qt = 0; qt < 2; ++qt) {
    const size_t row16 = (size_t)(Qw + qt * 16 + n16) * 16;
#pragma unroll
    for (int hf = 0; hf < 2; ++hf) {  // hf=0: k[0,32), hf=1: k[32,64)
      const size_t rb = row16 + hf * 8 + quad * 2;
      const f32x4 va = z4[rb];
      const f32x4 vb = z4[rb + 1];
      half8 H, L;
#pragma unroll
      for (int e = 0; e < 4; ++e) {
        const float fa = va[e], fb = vb[e];
        const _Float16 ha = (_Float16)fa, hb = (_Float16)fb;
        H[e] = ha; H[e + 4] = hb;
        L[e] = (_Float16)(fa - (float)ha);
        L[e + 4] = (_Float16)(fb - (float)hb);
      }
      if (hf == 0) { aH0[qt] = H; aL0[qt] = L; }
      else         { aH1[qt] = H; aL1[qt] = L; }
    }
  }

  float best[2][4];
  int bidx[2][4];
#pragma unroll
  for (int qt = 0; qt < 2; ++qt)
#pragma unroll
    for (int r = 0; r < 4; ++r) {
      best[qt][r] = -3.4e38f;
      bidx[qt][r] = 0;
    }

  const int Cjob = split * CSPLIT;
  const f32x4* __restrict__ cb4 = (const f32x4*)cb;
  const half8* __restrict__ Bs8 = (const half8*)Bs;

  for (int g = 0; g < NGROUP; ++g) {
    const int C0 = Cjob + g * GROUP;
    __syncthreads();
    // stage 128 code rows: f32 -> (h,l) f16, frag-contiguous + swizzle
#pragma unroll
    for (int p = 0; p < 8; ++p) {
      const int gg = t + 256 * p;  // flat f32x4 index in group
      const int r = gg >> 4;       // code row in group
      const int j4 = gg & 15;      // which f32x4 of the row (d=4*j4..)
      const int n = r & 15;
      const int tt = r >> 4;
      const int q = (j4 >> 1) & 3;
      const int ihalf = j4 & 1;
      const int frh = j4 >> 3;       // 0: d<32, 1: d>=32
      const int fs = frh * 4 + q;    // swizzle key
      const f32x4 v = cb4[(size_t)C0 * 16 + gg];
      half4v hh, ll;
#pragma unroll
      for (int e = 0; e < 4; ++e) {
        const float f = v[e];
        const _Float16 h = (_Float16)f;
        hh[e] = h;
        ll[e] = (_Float16)(f - (float)h);
      }
      const int nw = n ^ fs;
      _Float16* dsth = Bs + ((size_t)((tt * 4 + frh) * 64 + q * 16 + nw)) * 8 +
                       ihalf * 4;
      _Float16* dstl = Bs +
                       ((size_t)((tt * 4 + frh + 2) * 64 + q * 16 + nw)) * 8 +
                       ihalf * 4;
      *(half4v*)dsth = hh;
      *(half4v*)dstl = ll;
    }
    __syncthreads();
#pragma unroll
    for (int tt = 0; tt < NTILE; ++tt) {
      const int base = tt * 4 * 64 + quad * 16;
      const half8 b0 = Bs8[base + (n16 ^ quad)];              // Ch k[0,32)
      const half8 b1 = Bs8[base + 64 + (n16 ^ (4 + quad))];   // Ch k[32,64)
      const half8 b2 = Bs8[base + 128 + (n16 ^ quad)];        // Cl k[0,32)
      const half8 b3 = Bs8[base + 192 + (n16 ^ (4 + quad))];  // Cl k[32,64)
      const int c = C0 + tt * 16 + n16;
      const float cn = hcn[c];
#pragma unroll
      for (int qt = 0; qt < 2; ++qt) {
        f32x4 acc = {0.f, 0.f, 0.f, 0.f};
        acc = __builtin_amdgcn_mfma_f32_16x16x32_f16(aH0[qt], b0, acc, 0, 0, 0);
        acc = __builtin_amdgcn_mfma_f32_16x16x32_f16(aH1[qt], b1, acc, 0, 0, 0);
        acc = __builtin_amdgcn_mfma_f32_16x16x32_f16(aH0[qt], b2, acc, 0, 0, 0);
        acc = __builtin_amdgcn_mfma_f32_16x16x32_f16(aH1[qt], b3, acc, 0, 0, 0);
        acc = __builtin_amdgcn_mfma_f32_16x16x32_f16(aL0[qt], b0, acc, 0, 0, 0);
        acc = __builtin_amdgcn_mfma_f32_16x16x32_f16(aL1[qt], b1, acc, 0, 0, 0);
#pragma unroll
        for (int r = 0; r < 4; ++r) {
          const float u = acc[r] - cn;
          if (u > best[qt][r]) { best[qt][r] = u; bidx[qt][r] = c; }
        }
      }
    }
  }
#pragma unroll
  for (int qt = 0; qt < 2; ++qt)
#pragma unroll
    for (int r = 0; r < 4; ++r) {
      float u = best[qt][r];
      int c = bidx[qt][r];
#pragma unroll
      for (int off = 1; off < 16; off <<= 1) {
        const float u2 = __shfl_xor(u, off, 64);
        const int c2 = __shfl_xor(c, off, 64);
        if (u2 > u || (u2 == u && c2 < c)) { u = u2; c = c2; }
      }
      if (n16 == 0) {
        const int q = Qw + qt * 16 + quad * 4 + r;
        pmax[(size_t)split * NQ + q] = u;
        pidx[(size_t)split * NQ + q] = c;
      }
    }
}

__global__ __launch_bounds__(256) void k_assign(
    const float* __restrict__ z, const float* __restrict__ cb,
    const float* __restrict__ pmax, const int* __restrict__ pidx,
    float* __restrict__ out_zq, float* __restrict__ out_idx,
    float* __restrict__ dw, float* __restrict__ cs,
    float* __restrict__ parts) {
  const int t = threadIdx.x;
  const int d = t & 63;
  const int q = blockIdx.x * 4 + (t >> 6);

  const int s = d & 7;
  float v = pmax[(size_t)s * NQ + q];
  int i = pidx[(size_t)s * NQ + q];
#pragma unroll
  for (int off = 1; off < 8; off <<= 1) {
    const float v2 = __shfl_xor(v, off, 64);
    const int i2 = __shfl_xor(i, off, 64);
    if (v2 > v || (v2 == v && i2 < i)) { v = v2; i = i2; }
  }
  const int k = i;  // all lanes agree

  const float zv = z[(size_t)q * DD + d];
  const float cv = cb[(size_t)k * DD + d];
  out_zq[(size_t)q * DD + d] = cv;  // z + (z_q - z)
  const float diff = zv - cv;
  float sq = diff * diff;
#pragma unroll
  for (int off = 1; off < 64; off <<= 1) sq += __shfl_xor(sq, off, 64);
  if (d == 0) {
    out_idx[q] = (float)k;  // exact in f32 (k < 8192)
    atomicAdd(&cs[k], 1.0f);
    atomicAdd(&parts[blockIdx.x & 63], sq);
  }
  atomicAdd(&dw[(size_t)k * DD + d], zv);
}

// Fused newcs + finalout: n = 0.99*sum(ema_cs) + 0.01*NQ (sum(counts)==NQ).
__global__ __launch_bounds__(256) void k_final(
    const float* __restrict__ ema_cs, const float* __restrict__ cs,
    const float* __restrict__ ema_ws, const float* __restrict__ dw,
    const float* __restrict__ ema_sum, const float* __restrict__ parts,
    float* __restrict__ out_ncs, float* __restrict__ out_ncb,
    float* __restrict__ out_nws, float* __restrict__ out_loss) {
  const int i = blockIdx.x * 256 + threadIdx.x;
  const int k = i >> 6;
  const int d = i & 63;

  if (blockIdx.x == 0 && threadIdx.x < 64) {
    float sv = parts[threadIdx.x];
#pragma unroll
    for (int off = 1; off < 64; off <<= 1) sv += __shfl_xor(sv, off, 64);
    if (threadIdx.x == 0) *out_loss = 1.25f * sv * (1.0f / 1048576.0f);
  }

  const float n = 0.99f * (*ema_sum) + 0.01f * 16384.0f;
  const float v = 0.99f * ema_cs[k] + 0.01f * cs[k];
  if (d == 0) out_ncs[k] = v;
  const float smoothed = (v + 1e-5f) / (n + (float)KC * 1e-5f) * n;
  const float nws = 0.99f * ema_ws[i] + 0.01f * dw[i];
  out_nws[i] = nws;
  out_ncb[i] = nws / smoothed;
}

extern "C" void kernel_launch(void* const* d_in, const int* in_sizes, int n_in,
                              void* d_out, int out_size, void* d_ws,
                              size_t ws_size, hipStream_t stream) {
  const float* z = (const float*)d_in[0];
  const float* cb = (const float*)d_in[1];
  const float* ema_cs = (const float*)d_in[2];
  const float* ema_ws = (const float*)d_in[3];

  float* out = (float*)d_out;
  float* zq_out = out;              // 1048576
  float* loss_out = out + 1048576;  // 1
  float* idx_out = out + 1048577;   // 16384
  float* ncb_out = out + 1064961;   // 524288
  float* ncs_out = out + 1589249;   // 8192
  float* nws_out = out + 1597441;   // 524288

  float* ws = (float*)d_ws;
  float* dw = ws;                   // 524288
  float* cs = ws + 524288;          // 8192
  float* parts = ws + 532480;       // 64
  float* ema_sum = ws + 532544;     // 1
  float* hcn = ws + 532608;         // 8192
  float* pmax = ws + 540800;        // 131072
  int* pidx = (int*)(ws + 671872);  // 131072

  hipMemsetAsync(d_ws, 0, (size_t)532545 * sizeof(float), stream);

  k_prep<<<KC / 4, 256, 0, stream>>>(cb, ema_cs, hcn, ema_sum);
  k_mfma<<<dim3(NQ / 128, NSPLIT), 256, 0, stream>>>(z, cb, hcn, pmax, pidx);
  k_assign<<<NQ / 4, 256, 0, stream>>>(z, cb, pmax, pidx, zq_out, idx_out, dw,
                                       cs, parts);
  k_final<<<KC * DD / 256, 256, 0, stream>>>(ema_cs, cs, ema_ws, dw, ema_sum,
                                             parts, ncs_out, ncb_out, nws_out,
                                             loss_out);
}

// Round 10
// 222.453 us; speedup vs baseline: 2.8710x; 1.2303x over previous
//
#include <hip/hip_runtime.h>
#include <hip/hip_bf16.h>

// z: (8,2048,64) f32 -> N=16384, D=64 ; codebook: (8192,64) f32
// outputs (f32, concat): z_q_st[1048576], vq_loss[1], idx[16384],
//   new_codebook[524288], new_cs[8192], new_ws[524288]
//
// Distance argmin via f16-split MFMA: x = xh + xl. dot(x,c) ~= Xh.Ch + Xh.Cl
// + Xl.Ch. argmin ||x-c||^2 == argmax (dot - 0.5||c||^2).
// dw/cs are built by a k-partitioned gather (k_scatter) -- NO global atomics.

#define NQ 16384
#define KC 8192
#define DD 64
#define NSPLIT 8
#define CSPLIT (KC / NSPLIT)     // 1024 codes per block job
#define GROUP 128                // codes staged in LDS per barrier
#define NGROUP (CSPLIT / GROUP)  // 8
#define NTILE (GROUP / 16)       // 8 MFMA c-tiles per staged group

#define SC_BLOCKS 256
#define SC_CODES (KC / SC_BLOCKS)  // 32 codes per scatter block

typedef _Float16 half8 __attribute__((ext_vector_type(8)));
typedef _Float16 half4v __attribute__((ext_vector_type(4)));
typedef float f32x4 __attribute__((ext_vector_type(4)));

// ---------------- workspace layout (floats) ----------------
// [0)        dw          524288   (written by k_scatter, no memset needed)
// [524288)   cs          8192     (written by k_scatter)
// [532480)   parts       64       (sumsq spread buckets; memset)
// [532544)   ema_sum     1        (memset)
// [532608)   hcn         8192
// [540800)   pmax        131072   (8 x 16384 partial max-u)
// [671872)   pidx (int)  131072
// [802944)   idx_i (int) 16384

__global__ __launch_bounds__(256) void k_prep(
    const float* __restrict__ cb, const float* __restrict__ ema_cs,
    float* __restrict__ hcn, float* __restrict__ ema_sum) {
  const int b = blockIdx.x;
  const int t = threadIdx.x;
  const int w = t >> 6, d = t & 63;
  const int r = b * 4 + w;
  float v = cb[(size_t)r * DD + d];
  float s = v * v;
#pragma unroll
  for (int off = 1; off < 64; off <<= 1) s += __shfl_xor(s, off, 64);
  if (d == 0) hcn[r] = 0.5f * s;
  if (b < 32) {
    float su = ema_cs[b * 256 + t];
#pragma unroll
    for (int off = 1; off < 64; off <<= 1) su += __shfl_xor(su, off, 64);
    __shared__ float ss[4];
    if (d == 0) ss[w] = su;
    __syncthreads();
    if (t == 0) atomicAdd(ema_sum, ss[0] + ss[1] + ss[2] + ss[3]);
  }
}

// MFMA argmax (unchanged from passing R9). Wave = 32 queries, block = 1024
// codes. LDS frag-contiguous + XOR swizzle; lane-linear ds_read_b128.
__global__ __launch_bounds__(256) void k_mfma(
    const float* __restrict__ z, const float* __restrict__ cb,
    const float* __restrict__ hcn, float* __restrict__ pmax,
    int* __restrict__ pidx) {
  __shared__ _Float16 Bs[NTILE * 4 * 64 * 8];  // 32 KB
  const int t = threadIdx.x;
  const int lane = t & 63;
  const int w = t >> 6;
  const int split = blockIdx.y;
  const int Qw = blockIdx.x * 128 + w * 32;
  const int n16 = lane & 15;
  const int quad = lane >> 4;

  const f32x4* __restrict__ z4 = (const f32x4*)z;
  half8 aH0[2], aH1[2], aL0[2], aL1[2];
#pragma unroll
  for (int qt = 0; qt < 2; ++qt) {
    const size_t row16 = (size_t)(Qw + qt * 16 + n16) * 16;
#pragma unroll
    for (int hf = 0; hf < 2; ++hf) {
      const size_t rb = row16 + hf * 8 + quad * 2;
      const f32x4 va = z4[rb];
      const f32x4 vb = z4[rb + 1];
      half8 H, L;
#pragma unroll
      for (int e = 0; e < 4; ++e) {
        const float fa = va[e], fb = vb[e];
        const _Float16 ha = (_Float16)fa, hb = (_Float16)fb;
        H[e] = ha; H[e + 4] = hb;
        L[e] = (_Float16)(fa - (float)ha);
        L[e + 4] = (_Float16)(fb - (float)hb);
      }
      if (hf == 0) { aH0[qt] = H; aL0[qt] = L; }
      else         { aH1[qt] = H; aL1[qt] = L; }
    }
  }

  float best[2][4];
  int bidx[2][4];
#pragma unroll
  for (int qt = 0; qt < 2; ++qt)
#pragma unroll
    for (int r = 0; r < 4; ++r) {
      best[qt][r] = -3.4e38f;
      bidx[qt][r] = 0;
    }

  const int Cjob = split * CSPLIT;
  const f32x4* __restrict__ cb4 = (const f32x4*)cb;
  const half8* __restrict__ Bs8 = (const half8*)Bs;

  for (int g = 0; g < NGROUP; ++g) {
    const int C0 = Cjob + g * GROUP;
    __syncthreads();
#pragma unroll
    for (int p = 0; p < 8; ++p) {
      const int gg = t + 256 * p;
      const int r = gg >> 4;
      const int j4 = gg & 15;
      const int n = r & 15;
      const int tt = r >> 4;
      const int q = (j4 >> 1) & 3;
      const int ihalf = j4 & 1;
      const int frh = j4 >> 3;
      const int fs = frh * 4 + q;
      const f32x4 v = cb4[(size_t)C0 * 16 + gg];
      half4v hh, ll;
#pragma unroll
      for (int e = 0; e < 4; ++e) {
        const float f = v[e];
        const _Float16 h = (_Float16)f;
        hh[e] = h;
        ll[e] = (_Float16)(f - (float)h);
      }
      const int nw = n ^ fs;
      _Float16* dsth = Bs + ((size_t)((tt * 4 + frh) * 64 + q * 16 + nw)) * 8 +
                       ihalf * 4;
      _Float16* dstl = Bs +
                       ((size_t)((tt * 4 + frh + 2) * 64 + q * 16 + nw)) * 8 +
                       ihalf * 4;
      *(half4v*)dsth = hh;
      *(half4v*)dstl = ll;
    }
    __syncthreads();
#pragma unroll
    for (int tt = 0; tt < NTILE; ++tt) {
      const int base = tt * 4 * 64 + quad * 16;
      const half8 b0 = Bs8[base + (n16 ^ quad)];              // Ch k[0,32)
      const half8 b1 = Bs8[base + 64 + (n16 ^ (4 + quad))];   // Ch k[32,64)
      const half8 b2 = Bs8[base + 128 + (n16 ^ quad)];        // Cl k[0,32)
      const half8 b3 = Bs8[base + 192 + (n16 ^ (4 + quad))];  // Cl k[32,64)
      const int c = C0 + tt * 16 + n16;
      const float cn = hcn[c];
#pragma unroll
      for (int qt = 0; qt < 2; ++qt) {
        f32x4 acc = {0.f, 0.f, 0.f, 0.f};
        acc = __builtin_amdgcn_mfma_f32_16x16x32_f16(aH0[qt], b0, acc, 0, 0, 0);
        acc = __builtin_amdgcn_mfma_f32_16x16x32_f16(aH1[qt], b1, acc, 0, 0, 0);
        acc = __builtin_amdgcn_mfma_f32_16x16x32_f16(aH0[qt], b2, acc, 0, 0, 0);
        acc = __builtin_amdgcn_mfma_f32_16x16x32_f16(aH1[qt], b3, acc, 0, 0, 0);
        acc = __builtin_amdgcn_mfma_f32_16x16x32_f16(aL0[qt], b0, acc, 0, 0, 0);
        acc = __builtin_amdgcn_mfma_f32_16x16x32_f16(aL1[qt], b1, acc, 0, 0, 0);
#pragma unroll
        for (int r = 0; r < 4; ++r) {
          const float u = acc[r] - cn;
          if (u > best[qt][r]) { best[qt][r] = u; bidx[qt][r] = c; }
        }
      }
    }
  }
#pragma unroll
  for (int qt = 0; qt < 2; ++qt)
#pragma unroll
    for (int r = 0; r < 4; ++r) {
      float u = best[qt][r];
      int c = bidx[qt][r];
#pragma unroll
      for (int off = 1; off < 16; off <<= 1) {
        const float u2 = __shfl_xor(u, off, 64);
        const int c2 = __shfl_xor(c, off, 64);
        if (u2 > u || (u2 == u && c2 < c)) { u = u2; c = c2; }
      }
      if (n16 == 0) {
        const int q = Qw + qt * 16 + quad * 4 + r;
        pmax[(size_t)split * NQ + q] = u;
        pidx[(size_t)split * NQ + q] = c;
      }
    }
}

// q-partitioned: merge partial argmax, gather z_q, write idx (float + int),
// loss partial. ONE parts atomic per block; no dw/cs atomics.
__global__ __launch_bounds__(256) void k_assign(
    const float* __restrict__ z, const float* __restrict__ cb,
    const float* __restrict__ pmax, const int* __restrict__ pidx,
    float* __restrict__ out_zq, float* __restrict__ out_idx,
    int* __restrict__ idx_i, float* __restrict__ parts) {
  const int t = threadIdx.x;
  const int d = t & 63;
  const int w = t >> 6;
  const int q = blockIdx.x * 4 + w;

  const int s = d & 7;
  float v = pmax[(size_t)s * NQ + q];
  int i = pidx[(size_t)s * NQ + q];
#pragma unroll
  for (int off = 1; off < 8; off <<= 1) {
    const float v2 = __shfl_xor(v, off, 64);
    const int i2 = __shfl_xor(i, off, 64);
    if (v2 > v || (v2 == v && i2 < i)) { v = v2; i = i2; }
  }
  const int k = i;  // all lanes agree

  const float zv = z[(size_t)q * DD + d];
  const float cv = cb[(size_t)k * DD + d];
  out_zq[(size_t)q * DD + d] = cv;  // z + (z_q - z)
  const float diff = zv - cv;
  float sq = diff * diff;
#pragma unroll
  for (int off = 1; off < 64; off <<= 1) sq += __shfl_xor(sq, off, 64);
  __shared__ float ss[4];
  if (d == 0) {
    out_idx[q] = (float)k;  // exact in f32 (k < 8192)
    idx_i[q] = k;
    ss[w] = sq;
  }
  __syncthreads();
  if (t == 0)
    atomicAdd(&parts[blockIdx.x & 63], ss[0] + ss[1] + ss[2] + ss[3]);
}

// k-partitioned gather: block owns SC_CODES codes; scans idx stream, ballots
// hits, accumulates z rows into LDS (ds atomics), writes dw/cs chunk directly.
// Zero global atomics.
__global__ __launch_bounds__(256) void k_scatter(
    const float* __restrict__ z, const int* __restrict__ idx_i,
    float* __restrict__ dw, float* __restrict__ cs) {
  __shared__ float acc[SC_CODES * 64];  // 8 KB
  __shared__ int cnt[SC_CODES];
  const int t = threadIdx.x;
  const int k0 = blockIdx.x * SC_CODES;
  for (int i = t; i < SC_CODES * 64; i += 256) acc[i] = 0.f;
  if (t < SC_CODES) cnt[t] = 0;
  __syncthreads();

  const int w = t >> 6, lane = t & 63;
  const int qbase = w * (NQ / 4);
#pragma unroll 4
  for (int it = 0; it < NQ / 4 / 64; ++it) {  // 64 iterations
    const int q = qbase + it * 64 + lane;
    const int kv = idx_i[q];
    const bool hit = (unsigned)(kv - k0) < (unsigned)SC_CODES;
    unsigned long long m = __ballot(hit);
    while (m) {
      const int j = __ffsll((unsigned long long)m) - 1;
      m &= m - 1;
      const int kj = __shfl(kv, j, 64);
      const int qj = qbase + it * 64 + j;
      const float zvj = z[(size_t)qj * DD + lane];
      atomicAdd(&acc[(kj - k0) * 64 + lane], zvj);
      if (lane == 0) atomicAdd(&cnt[kj - k0], 1);
    }
  }
  __syncthreads();
  for (int i = t; i < SC_CODES * 64; i += 256)
    dw[(size_t)k0 * 64 + i] = acc[i];
  if (t < SC_CODES) cs[k0 + t] = (float)cnt[t];
}

// Fused newcs + finalout: n = 0.99*sum(ema_cs) + 0.01*NQ (sum(counts)==NQ).
__global__ __launch_bounds__(256) void k_final(
    const float* __restrict__ ema_cs, const float* __restrict__ cs,
    const float* __restrict__ ema_ws, const float* __restrict__ dw,
    const float* __restrict__ ema_sum, const float* __restrict__ parts,
    float* __restrict__ out_ncs, float* __restrict__ out_ncb,
    float* __restrict__ out_nws, float* __restrict__ out_loss) {
  const int i = blockIdx.x * 256 + threadIdx.x;
  const int k = i >> 6;
  const int d = i & 63;

  if (blockIdx.x == 0 && threadIdx.x < 64) {
    float sv = parts[threadIdx.x];
#pragma unroll
    for (int off = 1; off < 64; off <<= 1) sv += __shfl_xor(sv, off, 64);
    if (threadIdx.x == 0) *out_loss = 1.25f * sv * (1.0f / 1048576.0f);
  }

  const float n = 0.99f * (*ema_sum) + 0.01f * 16384.0f;
  const float v = 0.99f * ema_cs[k] + 0.01f * cs[k];
  if (d == 0) out_ncs[k] = v;
  const float smoothed = (v + 1e-5f) / (n + (float)KC * 1e-5f) * n;
  const float nws = 0.99f * ema_ws[i] + 0.01f * dw[i];
  out_nws[i] = nws;
  out_ncb[i] = nws / smoothed;
}

extern "C" void kernel_launch(void* const* d_in, const int* in_sizes, int n_in,
                              void* d_out, int out_size, void* d_ws,
                              size_t ws_size, hipStream_t stream) {
  const float* z = (const float*)d_in[0];
  const float* cb = (const float*)d_in[1];
  const float* ema_cs = (const float*)d_in[2];
  const float* ema_ws = (const float*)d_in[3];

  float* out = (float*)d_out;
  float* zq_out = out;              // 1048576
  float* loss_out = out + 1048576;  // 1
  float* idx_out = out + 1048577;   // 16384
  float* ncb_out = out + 1064961;   // 524288
  float* ncs_out = out + 1589249;   // 8192
  float* nws_out = out + 1597441;   // 524288

  float* ws = (float*)d_ws;
  float* dw = ws;                    // 524288
  float* cs = ws + 524288;           // 8192
  float* parts = ws + 532480;        // 64
  float* ema_sum = ws + 532544;      // 1
  float* hcn = ws + 532608;          // 8192
  float* pmax = ws + 540800;         // 131072
  int* pidx = (int*)(ws + 671872);   // 131072
  int* idx_i = (int*)(ws + 802944);  // 16384

  // zero parts + ema_sum only (dw/cs are fully written by k_scatter)
  hipMemsetAsync(ws + 532480, 0, 65 * sizeof(float), stream);

  k_prep<<<KC / 4, 256, 0, stream>>>(cb, ema_cs, hcn, ema_sum);
  k_mfma<<<dim3(NQ / 128, NSPLIT), 256, 0, stream>>>(z, cb, hcn, pmax, pidx);
  k_assign<<<NQ / 4, 256, 0, stream>>>(z, cb, pmax, pidx, zq_out, idx_out,
                                       idx_i, parts);
  k_scatter<<<SC_BLOCKS, 256, 0, stream>>>(z, idx_i, dw, cs);
  k_final<<<KC * DD / 256, 256, 0, stream>>>(ema_cs, cs, ema_ws, dw, ema_sum,
                                             parts, ncs_out, ncb_out, nws_out,
                                             loss_out);
}

// Round 11
// 152.022 us; speedup vs baseline: 4.2012x; 1.4633x over previous
//
#include <hip/hip_runtime.h>
#include <hip/hip_bf16.h>

// z: (8,2048,64) f32 -> N=16384, D=64 ; codebook: (8192,64) f32
// outputs (f32, concat): z_q_st[1048576], vq_loss[1], idx[16384],
//   new_codebook[524288], new_cs[8192], new_ws[524288]
//
// Distance argmin via f16-split MFMA: x = xh + xl. dot(x,c) ~= Xh.Ch + Xh.Cl
// + Xl.Ch. argmin ||x-c||^2 == argmax (dot - 0.5||c||^2); -0.5||c||^2 is
// folded into the MFMA accumulator init. The f16-split codebook is
// precomputed ONCE (k_prep) into a swizzled image whose group blocks are
// byte-identical to the LDS layout -> k_mfma stages via global_load_lds DMA.

#define NQ 16384
#define KC 8192
#define DD 64
#define NSPLIT 8
#define CSPLIT (KC / NSPLIT)     // 1024 codes per block job
#define GROUP 128                // codes staged in LDS per barrier
#define NGROUP (CSPLIT / GROUP)  // 8
#define NTILE (GROUP / 16)       // 8 MFMA c-tiles per staged group
#define IMGH 16384               // halves per group image (32 KB)

#define SC_BLOCKS 256
#define SC_CODES (KC / SC_BLOCKS)  // 32 codes per tail block

typedef _Float16 half8 __attribute__((ext_vector_type(8)));
typedef _Float16 half4v __attribute__((ext_vector_type(4)));
typedef float f32x4 __attribute__((ext_vector_type(4)));
typedef unsigned int u32;

__device__ __forceinline__ void async_copy16(const _Float16* g, _Float16* l) {
  __builtin_amdgcn_global_load_lds(
      (const __attribute__((address_space(1))) u32*)(const void*)g,
      (__attribute__((address_space(3))) u32*)(void*)l, 16, 0, 0);
}

// ---------------- workspace layout (floats) ----------------
// [0)       nhcn    8192    (-0.5*||c||^2)
// [8192)    epart   32      (ema_cs partial sums, non-atomic)
// [8256)    parts   4096    (loss partials, one per k_assign block)
// [12352)   pmax    131072  (8 x 16384 partial max-u)
// [143424)  pidx    131072  (int)
// [274496)  idx_i   16384   (int)
// [290880)  Cxs     524288  (f16 x 1048576: 64 group images x 32 KB)

// k_prep: swizzled f16-split codebook image + nhcn + ema partials.
// thread = (code c, j4) ; c = gid>>4, j4 = gid&15 covers f32x4 d=4*j4..
__global__ __launch_bounds__(256) void k_prep(
    const float* __restrict__ cb, const float* __restrict__ ema_cs,
    _Float16* __restrict__ Cxs, float* __restrict__ nhcn,
    float* __restrict__ epart) {
  const int t = threadIdx.x;
  const int gid = blockIdx.x * 256 + t;
  const int c = gid >> 4;
  const int j4 = gid & 15;

  const f32x4 v = ((const f32x4*)cb)[gid];
  half4v hh, ll;
  float s = 0.f;
#pragma unroll
  for (int e = 0; e < 4; ++e) {
    const float f = v[e];
    const _Float16 h = (_Float16)f;
    hh[e] = h;
    ll[e] = (_Float16)(f - (float)h);
    s = fmaf(f, f, s);
  }
  // swizzled slot (identical formula to the R9/R10 in-kernel staging)
  const int r = c & 127;           // row in group
  const int tt = r >> 4;
  const int n = r & 15;
  const int q = (j4 >> 1) & 3;
  const int ihalf = j4 & 1;
  const int frh = j4 >> 3;
  const int fs = frh * 4 + q;
  const int nw = n ^ fs;
  _Float16* img = Cxs + (size_t)(c >> 7) * IMGH;
  *(half4v*)(img + ((size_t)((tt * 4 + frh) * 64 + q * 16 + nw)) * 8 +
             ihalf * 4) = hh;
  *(half4v*)(img + ((size_t)((tt * 4 + frh + 2) * 64 + q * 16 + nw)) * 8 +
             ihalf * 4) = ll;

  // row sumsq: reduce across the 16 lanes of this row (lanes j4=0..15)
#pragma unroll
  for (int off = 1; off < 16; off <<= 1) s += __shfl_xor(s, off, 64);
  if (j4 == 0) nhcn[c] = -0.5f * s;

  // ema partials: blocks 0..31 each reduce 256 values (non-atomic write)
  if (blockIdx.x < 32) {
    float su = ema_cs[blockIdx.x * 256 + t];
#pragma unroll
    for (int off = 1; off < 64; off <<= 1) su += __shfl_xor(su, off, 64);
    __shared__ float ss[4];
    if ((t & 63) == 0) ss[t >> 6] = su;
    __syncthreads();
    if (t == 0) epart[blockIdx.x] = ss[0] + ss[1] + ss[2] + ss[3];
  }
}

// MFMA argmax. Wave = 32 queries (2 16x16 q-tiles), block job = 1024 codes.
// Staging = linear global_load_lds DMA of the precomputed group image.
// acc init = -0.5||c||^2 -> u = acc[r] directly after the 6 MFMAs.
__global__ __launch_bounds__(256, 4) void k_mfma(
    const float* __restrict__ z, const _Float16* __restrict__ Cxs,
    const float* __restrict__ nhcn, float* __restrict__ pmax,
    int* __restrict__ pidx) {
  __shared__ _Float16 Bs[IMGH];  // 32 KB
  const int t = threadIdx.x;
  const int lane = t & 63;
  const int w = t >> 6;
  const int split = blockIdx.y;
  const int Qw = blockIdx.x * 128 + w * 32;
  const int n16 = lane & 15;
  const int quad = lane >> 4;

  // A-frags: z rows -> f16 split in registers (layout: lane holds
  // A[m=lane&15][k=(lane>>4)*8+j]; frag hf covers k/d in [32*hf, 32*hf+32)).
  const f32x4* __restrict__ z4 = (const f32x4*)z;
  half8 aH0[2], aH1[2], aL0[2], aL1[2];
#pragma unroll
  for (int qt = 0; qt < 2; ++qt) {
    const size_t row16 = (size_t)(Qw + qt * 16 + n16) * 16;
#pragma unroll
    for (int hf = 0; hf < 2; ++hf) {
      const size_t rb = row16 + hf * 8 + quad * 2;
      const f32x4 va = z4[rb];
      const f32x4 vb = z4[rb + 1];
      half8 H, L;
#pragma unroll
      for (int e = 0; e < 4; ++e) {
        const float fa = va[e], fb = vb[e];
        const _Float16 ha = (_Float16)fa, hb = (_Float16)fb;
        H[e] = ha; H[e + 4] = hb;
        L[e] = (_Float16)(fa - (float)ha);
        L[e + 4] = (_Float16)(fb - (float)hb);
      }
      if (hf == 0) { aH0[qt] = H; aL0[qt] = L; }
      else         { aH1[qt] = H; aL1[qt] = L; }
    }
  }

  float best[2][4];
  int bidx[2][4];
#pragma unroll
  for (int qt = 0; qt < 2; ++qt)
#pragma unroll
    for (int r = 0; r < 4; ++r) {
      best[qt][r] = -3.4e38f;
      bidx[qt][r] = 0;
    }

  const half8* __restrict__ Bs8 = (const half8*)Bs;

  for (int g = 0; g < NGROUP; ++g) {
    const int C0 = split * CSPLIT + g * GROUP;
    const _Float16* gimg = Cxs + (size_t)(split * NGROUP + g) * IMGH;
    __syncthreads();
#pragma unroll
    for (int p = 0; p < 8; ++p) {
      const int off = (t + 256 * p) * 8;  // halves
      async_copy16(gimg + off, Bs + off);
    }
    __syncthreads();
#pragma unroll
    for (int tt = 0; tt < NTILE; ++tt) {
      const int base = tt * 4 * 64 + quad * 16;
      const half8 b0 = Bs8[base + (n16 ^ quad)];              // Ch k[0,32)
      const half8 b1 = Bs8[base + 64 + (n16 ^ (4 + quad))];   // Ch k[32,64)
      const half8 b2 = Bs8[base + 128 + (n16 ^ quad)];        // Cl k[0,32)
      const half8 b3 = Bs8[base + 192 + (n16 ^ (4 + quad))];  // Cl k[32,64)
      const int c = C0 + tt * 16 + n16;
      const float nc = nhcn[c];
#pragma unroll
      for (int qt = 0; qt < 2; ++qt) {
        f32x4 acc = {nc, nc, nc, nc};
        acc = __builtin_amdgcn_mfma_f32_16x16x32_f16(aH0[qt], b0, acc, 0, 0, 0);
        acc = __builtin_amdgcn_mfma_f32_16x16x32_f16(aH1[qt], b1, acc, 0, 0, 0);
        acc = __builtin_amdgcn_mfma_f32_16x16x32_f16(aH0[qt], b2, acc, 0, 0, 0);
        acc = __builtin_amdgcn_mfma_f32_16x16x32_f16(aH1[qt], b3, acc, 0, 0, 0);
        acc = __builtin_amdgcn_mfma_f32_16x16x32_f16(aL0[qt], b0, acc, 0, 0, 0);
        acc = __builtin_amdgcn_mfma_f32_16x16x32_f16(aL1[qt], b1, acc, 0, 0, 0);
#pragma unroll
        for (int r = 0; r < 4; ++r) {
          const float u = acc[r];
          if (u > best[qt][r]) { best[qt][r] = u; bidx[qt][r] = c; }
        }
      }
    }
  }
#pragma unroll
  for (int qt = 0; qt < 2; ++qt)
#pragma unroll
    for (int r = 0; r < 4; ++r) {
      float u = best[qt][r];
      int c = bidx[qt][r];
#pragma unroll
      for (int off = 1; off < 16; off <<= 1) {
        const float u2 = __shfl_xor(u, off, 64);
        const int c2 = __shfl_xor(c, off, 64);
        if (u2 > u || (u2 == u && c2 < c)) { u = u2; c = c2; }
      }
      if (n16 == 0) {
        const int q = Qw + qt * 16 + quad * 4 + r;
        pmax[(size_t)split * NQ + q] = u;
        pidx[(size_t)split * NQ + q] = c;
      }
    }
}

// q-partitioned: merge partial argmax, gather z_q, write idx, loss partial
// (non-atomic, one float per block).
__global__ __launch_bounds__(256) void k_assign(
    const float* __restrict__ z, const float* __restrict__ cb,
    const float* __restrict__ pmax, const int* __restrict__ pidx,
    float* __restrict__ out_zq, float* __restrict__ out_idx,
    int* __restrict__ idx_i, float* __restrict__ parts) {
  const int t = threadIdx.x;
  const int d = t & 63;
  const int w = t >> 6;
  const int q = blockIdx.x * 4 + w;

  const int s = d & 7;
  float v = pmax[(size_t)s * NQ + q];
  int i = pidx[(size_t)s * NQ + q];
#pragma unroll
  for (int off = 1; off < 8; off <<= 1) {
    const float v2 = __shfl_xor(v, off, 64);
    const int i2 = __shfl_xor(i, off, 64);
    if (v2 > v || (v2 == v && i2 < i)) { v = v2; i = i2; }
  }
  const int k = i;  // all lanes agree

  const float zv = z[(size_t)q * DD + d];
  const float cv = cb[(size_t)k * DD + d];
  out_zq[(size_t)q * DD + d] = cv;  // z + (z_q - z)
  const float diff = zv - cv;
  float sq = diff * diff;
#pragma unroll
  for (int off = 1; off < 64; off <<= 1) sq += __shfl_xor(sq, off, 64);
  __shared__ float ss[4];
  if (d == 0) {
    out_idx[q] = (float)k;  // exact in f32 (k < 8192)
    idx_i[q] = k;
    ss[w] = sq;
  }
  __syncthreads();
  if (t == 0) parts[blockIdx.x] = ss[0] + ss[1] + ss[2] + ss[3];
}

// k-partitioned tail: gather dw/cs for 32 owned codes into LDS (ballot scan
// of idx stream), then compute new_cs/new_codebook/new_ws directly. Block 0
// also reduces the loss partials. Zero global atomics anywhere.
__global__ __launch_bounds__(256) void k_tail(
    const float* __restrict__ z, const int* __restrict__ idx_i,
    const float* __restrict__ ema_cs, const float* __restrict__ ema_ws,
    const float* __restrict__ epart, const float* __restrict__ parts,
    float* __restrict__ out_ncs, float* __restrict__ out_ncb,
    float* __restrict__ out_nws, float* __restrict__ out_loss) {
  __shared__ float acc[SC_CODES * 64];  // 8 KB
  __shared__ int cnt[SC_CODES];
  const int t = threadIdx.x;
  const int k0 = blockIdx.x * SC_CODES;
  for (int i = t; i < SC_CODES * 64; i += 256) acc[i] = 0.f;
  if (t < SC_CODES) cnt[t] = 0;
  __syncthreads();

  const int w = t >> 6, lane = t & 63;
  const int qbase = w * (NQ / 4);
#pragma unroll 4
  for (int it = 0; it < NQ / 4 / 64; ++it) {  // 64 iterations
    const int q = qbase + it * 64 + lane;
    const int kv = idx_i[q];
    const bool hit = (unsigned)(kv - k0) < (unsigned)SC_CODES;
    unsigned long long m = __ballot(hit);
    while (m) {
      const int j = __ffsll(m) - 1;
      m &= m - 1;
      const int kj = __shfl(kv, j, 64);
      const int qj = qbase + it * 64 + j;
      const float zvj = z[(size_t)qj * DD + lane];
      atomicAdd(&acc[(kj - k0) * 64 + lane], zvj);
      if (lane == 0) atomicAdd(&cnt[kj - k0], 1);
    }
  }
  __syncthreads();

  // n = 0.99*sum(ema_cs) + 0.01*NQ  (sum(counts) == NQ exactly)
  float esum = 0.f;
#pragma unroll
  for (int b = 0; b < 32; ++b) esum += epart[b];
  const float n = 0.99f * esum + 0.01f * 16384.0f;

  for (int i = t; i < SC_CODES * 64; i += 256) {
    const int kl = i >> 6;
    const int k = k0 + kl;
    const float v = 0.99f * ema_cs[k] + 0.01f * (float)cnt[kl];
    const float smoothed = (v + 1e-5f) / (n + (float)KC * 1e-5f) * n;
    const float nws = 0.99f * ema_ws[(size_t)k * DD + (i & 63)] + 0.01f * acc[i];
    out_nws[(size_t)k0 * DD + i] = nws;
    out_ncb[(size_t)k0 * DD + i] = nws / smoothed;
  }
  if (t < SC_CODES)
    out_ncs[k0 + t] = 0.99f * ema_cs[k0 + t] + 0.01f * (float)cnt[t];

  if (blockIdx.x == 0) {
    __syncthreads();  // acc no longer needed; reuse as reduce scratch
    float s = 0.f;
    for (int i = t; i < 4096; i += 256) s += parts[i];
#pragma unroll
    for (int off = 1; off < 64; off <<= 1) s += __shfl_xor(s, off, 64);
    if ((t & 63) == 0) acc[t >> 6] = s;
    __syncthreads();
    if (t == 0)
      *out_loss = 1.25f * (acc[0] + acc[1] + acc[2] + acc[3]) *
                  (1.0f / 1048576.0f);
  }
}

extern "C" void kernel_launch(void* const* d_in, const int* in_sizes, int n_in,
                              void* d_out, int out_size, void* d_ws,
                              size_t ws_size, hipStream_t stream) {
  const float* z = (const float*)d_in[0];
  const float* cb = (const float*)d_in[1];
  const float* ema_cs = (const float*)d_in[2];
  const float* ema_ws = (const float*)d_in[3];

  float* out = (float*)d_out;
  float* zq_out = out;              // 1048576
  float* loss_out = out + 1048576;  // 1
  float* idx_out = out + 1048577;   // 16384
  float* ncb_out = out + 1064961;   // 524288
  float* ncs_out = out + 1589249;   // 8192
  float* nws_out = out + 1597441;   // 524288

  float* ws = (float*)d_ws;
  float* nhcn = ws;                        // 8192
  float* epart = ws + 8192;                // 32
  float* parts = ws + 8256;                // 4096
  float* pmax = ws + 12352;                // 131072
  int* pidx = (int*)(ws + 143424);         // 131072
  int* idx_i = (int*)(ws + 274496);        // 16384
  _Float16* Cxs = (_Float16*)(ws + 290880);  // 1048576 halves (2 MB)

  k_prep<<<KC * 16 / 256, 256, 0, stream>>>(cb, ema_cs, Cxs, nhcn, epart);
  k_mfma<<<dim3(NQ / 128, NSPLIT), 256, 0, stream>>>(z, Cxs, nhcn, pmax, pidx);
  k_assign<<<NQ / 4, 256, 0, stream>>>(z, cb, pmax, pidx, zq_out, idx_out,
                                       idx_i, parts);
  k_tail<<<SC_BLOCKS, 256, 0, stream>>>(z, idx_i, ema_cs, ema_ws, epart, parts,
                                        ncs_out, ncb_out, nws_out, loss_out);
}